// Round 4
// baseline (96.004 us; speedup 1.0000x reference)
//
#include <hip/hip_runtime.h>
#include <math.h>

// Problem constants
#define B       200
#define V       40
#define FIN     16
#define H       128
#define NSW     12
#define NE      40
#define M       52      // NE + NSW
#define MLP_HID 1024
#define OUTD    104     // M + V + NSW
#define MLP_IN  6656    // (NSW + V) * H
#define ZDIM    144
#define ZCDIM   132

typedef __attribute__((ext_vector_type(8))) short bf16x8;
typedef __attribute__((ext_vector_type(4))) float f32x4;

__device__ __forceinline__ float sigmoidf(float x) {
    return 1.0f / (1.0f + expf(-x));
}
__device__ __forceinline__ unsigned short f2b(float x) {  // fp32 -> bf16 RNE
    unsigned int u = __float_as_uint(x);
    u += 0x7fffu + ((u >> 16) & 1u);
    return (unsigned short)(u >> 16);
}
__device__ __forceinline__ float b2f(unsigned short s) {
    return __uint_as_float(((unsigned int)s) << 16);
}

// ---------------- weight prep (merged) ----------------
// x<208: W1 (6656x1024 f32) -> W1t (1024x6656 bf16), 32x32 LDS tiles
// x==208: {WU1,WV1,WB1,WC1} -> Wt512[col][k] bf16, col = m*128+h, k=f
__global__ __launch_bounds__(256) void k_prep(const float* __restrict__ W1,
        const float* __restrict__ WU, const float* __restrict__ WV,
        const float* __restrict__ WB, const float* __restrict__ WC,
        unsigned short* __restrict__ W1t, unsigned short* __restrict__ Wt512) {
    int tid = threadIdx.x;
    if (blockIdx.x < 208) {
        int k0 = blockIdx.x * 32, n0 = blockIdx.y * 32;
        __shared__ float tile[32][33];
        int c = tid & 31, r8 = tid >> 5;
#pragma unroll
        for (int i = 0; i < 4; ++i) {
            int r = r8 + i * 8;
            tile[r][c] = W1[(size_t)(k0 + r) * MLP_HID + n0 + c];
        }
        __syncthreads();
#pragma unroll
        for (int i = 0; i < 4; ++i) {
            int rr = r8 + i * 8;
            W1t[(size_t)(n0 + rr) * MLP_IN + k0 + c] = f2b(tile[c][rr]);
        }
    } else {
        int base = (blockIdx.y * 256 + tid) * 8;
#pragma unroll
        for (int i = 0; i < 8; ++i) {
            int o = base + i;                 // < 512*128
            int col = o >> 7, f = o & 127;
            int m = col >> 7, h = col & 127;
            const float* Ws = (m == 0) ? WU : (m == 1) ? WV : (m == 2) ? WB : WC;
            Wt512[o] = f2b(Ws[f * H + h]);
        }
    }
}

// ---------------- fused layer 0: proj0 + comb0 + sA1 ----------------
// one block per batch, 512 threads, ~128.5 KB LDS
__global__ __launch_bounds__(512) void k_l0(const float* __restrict__ x,
        const int* __restrict__ ei, const int* __restrict__ si,
        const float* __restrict__ embed,
        const float* __restrict__ WU0, const float* __restrict__ WV0,
        const float* __restrict__ WB0, const float* __restrict__ WC0,
        const float* __restrict__ WA0, const float* __restrict__ WA1,
        unsigned short* __restrict__ x1b, unsigned short* __restrict__ e0rb,
        float* __restrict__ sA1) {
    int b = blockIdx.x;
    int tid = threadIdx.x;
    __shared__ unsigned short uvbc[V * 512];   // 40 KB  [row][m*128+h] bf16
    __shared__ float msg[4][V][H];             // 80 KB
    __shared__ float xs[V * FIN];              // 2.5 KB
    __shared__ unsigned short e0s[NSW * H];    // 3 KB  relu(e0) bf16

    for (int i = tid; i < V * FIN; i += 512) xs[i] = x[(size_t)b * V * FIN + i];
    __syncthreads();

    // projections: thread owns column (m,h); loop over 40 rows
    {
        int m = tid >> 7, hh = tid & 127;
        const float* Wm = (m == 0) ? WU0 : (m == 1) ? WV0 : (m == 2) ? WB0 : WC0;
        float w[FIN];
#pragma unroll
        for (int f = 0; f < FIN; ++f) w[f] = Wm[f * H + hh];
        for (int r = 0; r < V; ++r) {
            float acc = 0.f;
#pragma unroll
            for (int f = 0; f < FIN; ++f) acc += xs[r * FIN + f] * w[f];
            uvbc[r * 512 + tid] = f2b(acc);
        }
    }

    int h = tid & 127, sub = tid >> 7;
    // zero own msg column (only this thread ever accumulates into it)
    for (int i = 0; i < V; ++i) msg[sub][i][h] = 0.f;
    __syncthreads();   // uvbc ready

    float sA0 = 0.f;
#pragma unroll
    for (int f = 0; f < FIN; ++f) sA0 += embed[FIN + f] * WA0[f * H + h];

    for (int e = sub * 10; e < sub * 10 + 10; ++e) {
        int i = ei[e], j = ei[NE + e];
        msg[sub][i][h] += b2f(uvbc[j * 512 + 128 + h]);   // Vx[j]
        msg[sub][j][h] += b2f(uvbc[i * 512 + 128 + h]);
    }
    for (int k = sub * 3; k < sub * 3 + 3; ++k) {
        int i = si[k], j = si[NSW + k];
        float e0 = sA0 + b2f(uvbc[i * 512 + 256 + h]) + b2f(uvbc[j * 512 + 384 + h]);
        float g = sigmoidf(e0);
        msg[sub][i][h] += g * b2f(uvbc[j * 512 + 128 + h]);
        unsigned short r = f2b(fmaxf(e0, 0.f));
        e0s[k * H + h] = r;
        e0rb[(size_t)(b * NSW + k) * H + h] = r;
    }
    __syncthreads();

    for (int i = sub * 10; i < sub * 10 + 10; ++i) {
        float v = b2f(uvbc[i * 512 + h]) + msg[0][i][h] + msg[1][i][h] + msg[2][i][h] + msg[3][i][h];
        x1b[(size_t)(b * V + i) * H + h] = f2b(fmaxf(v, 0.f));   // layer 0: no residual
    }

    // sA1 = relu(e0) @ WA1  (12x128 per batch)
    for (int o = tid; o < NSW * H; o += 512) {
        int k = o >> 7, hh = o & 127;
        float acc = 0.f;
#pragma unroll 8
        for (int f = 0; f < H; ++f) acc += b2f(e0s[k * H + f]) * WA1[f * H + hh];
        sA1[(size_t)b * NSW * H + o] = acc;
    }
}

// ---------------- layer-1 combine ----------------
__global__ __launch_bounds__(512) void k_comb1(const int* __restrict__ ei,
        const int* __restrict__ si, const float* __restrict__ sA1,
        const unsigned short* __restrict__ uvbc_g, const unsigned short* __restrict__ x1b,
        const unsigned short* __restrict__ e0rb, unsigned short* __restrict__ Abf) {
    int b = blockIdx.x;
    int tid = threadIdx.x;
    int h = tid & 127, sub = tid >> 7;
    __shared__ float msg[4][V][H];
    for (int i = 0; i < V; ++i) msg[sub][i][h] = 0.f;

    const unsigned short* base = uvbc_g + (size_t)b * V * 512;
    for (int e = sub * 10; e < sub * 10 + 10; ++e) {
        int i = ei[e], j = ei[NE + e];
        msg[sub][i][h] += b2f(base[j * 512 + 128 + h]);
        msg[sub][j][h] += b2f(base[i * 512 + 128 + h]);
    }
    for (int k = sub * 3; k < sub * 3 + 3; ++k) {
        int i = si[k], j = si[NSW + k];
        float e1 = sA1[(size_t)(b * NSW + k) * H + h]
                 + b2f(base[i * 512 + 256 + h]) + b2f(base[j * 512 + 384 + h]);
        float g = sigmoidf(e1);
        msg[sub][i][h] += g * b2f(base[j * 512 + 128 + h]);
        float s1 = b2f(e0rb[(size_t)(b * NSW + k) * H + h]);
        Abf[(size_t)b * MLP_IN + k * H + h] = f2b(s1 + fmaxf(e1, 0.f));  // s2 at switch
    }
    __syncthreads();
    for (int i = sub * 10; i < sub * 10 + 10; ++i) {
        float xh = b2f(base[i * 512 + h]) + msg[0][i][h] + msg[1][i][h] + msg[2][i][h] + msg[3][i][h];
        float x2 = b2f(x1b[(size_t)(b * V + i) * H + h]) + fmaxf(xh, 0.f);  // residual
        Abf[(size_t)b * MLP_IN + NSW * H + i * H + h] = f2b(x2);
    }
}

// ---------------- generic bf16 MFMA GEMM ----------------
// C[MxN] = A[MxK](bf16,rowmajor) @ Bt[NxK](bf16,rowmajor)^T
// MODE 1: write bf16 C.  MODE 2: write f32 split-K partial[z].
template<int MODE>
__global__ __launch_bounds__(256) void k_gemm(const unsigned short* __restrict__ A,
        const unsigned short* __restrict__ Bt, void* __restrict__ Cout,
        int K, int nk, int ldc) {
    int tid = threadIdx.x;
    int lane = tid & 63, wv = tid >> 6;
    int wr = (wv >> 1) * 32, wc = (wv & 1) * 32;
    int n0 = blockIdx.x * 64, m0 = blockIdx.y * 64;
    size_t kbase = (size_t)blockIdx.z * nk * 32;

    __shared__ __align__(16) unsigned short a_lds[64 * 40];
    __shared__ __align__(16) unsigned short b_lds[64 * 40];

    f32x4 acc00 = {0,0,0,0}, acc01 = {0,0,0,0}, acc10 = {0,0,0,0}, acc11 = {0,0,0,0};

    int srow = tid >> 2, sseg = tid & 3;
    const int4* gA = (const int4*)(A + (size_t)(m0 + srow) * K + kbase + sseg * 8);
    const int4* gB = (const int4*)(Bt + (size_t)(n0 + srow) * K + kbase + sseg * 8);
    int lws = srow * 40 + sseg * 8;

    int a_off = (wr + (lane & 15)) * 40 + (lane >> 4) * 8;
    int b_off = (wc + (lane & 15)) * 40 + (lane >> 4) * 8;

    int4 ra = gA[0], rb = gB[0];
    for (int kk = 0; kk < nk; ++kk) {
        *(int4*)&a_lds[lws] = ra;
        *(int4*)&b_lds[lws] = rb;
        __syncthreads();
        if (kk + 1 < nk) { ra = gA[(kk + 1) * 4]; rb = gB[(kk + 1) * 4]; }
        bf16x8 a0 = *(const bf16x8*)&a_lds[a_off];
        bf16x8 a1 = *(const bf16x8*)&a_lds[a_off + 16 * 40];
        bf16x8 b0 = *(const bf16x8*)&b_lds[b_off];
        bf16x8 b1 = *(const bf16x8*)&b_lds[b_off + 16 * 40];
        acc00 = __builtin_amdgcn_mfma_f32_16x16x32_bf16(a0, b0, acc00, 0, 0, 0);
        acc01 = __builtin_amdgcn_mfma_f32_16x16x32_bf16(a0, b1, acc01, 0, 0, 0);
        acc10 = __builtin_amdgcn_mfma_f32_16x16x32_bf16(a1, b0, acc10, 0, 0, 0);
        acc11 = __builtin_amdgcn_mfma_f32_16x16x32_bf16(a1, b1, acc11, 0, 0, 0);
        __syncthreads();
    }

    int crow = (lane >> 4) * 4;
    int ccol = lane & 15;
    int row0 = m0 + wr + crow, row1 = row0 + 16;
    int col0 = n0 + wc + ccol, col1 = col0 + 16;
    if (MODE == 1) {
        unsigned short* dst = (unsigned short*)Cout;
#pragma unroll
        for (int r = 0; r < 4; ++r) {
            dst[(size_t)(row0 + r) * ldc + col0] = f2b(acc00[r]);
            dst[(size_t)(row0 + r) * ldc + col1] = f2b(acc01[r]);
            dst[(size_t)(row1 + r) * ldc + col0] = f2b(acc10[r]);
            dst[(size_t)(row1 + r) * ldc + col1] = f2b(acc11[r]);
        }
    } else {
        float* dst = (float*)Cout + (size_t)blockIdx.z * (gridDim.y * 64) * ldc;
#pragma unroll
        for (int r = 0; r < 4; ++r) {
            dst[(size_t)(row0 + r) * ldc + col0] = acc00[r];
            dst[(size_t)(row0 + r) * ldc + col1] = acc01[r];
            dst[(size_t)(row1 + r) * ldc + col0] = acc10[r];
            dst[(size_t)(row1 + r) * ldc + col1] = acc11[r];
        }
    }
}

// ---------------- fused head: split-K reduce + W2 GEMV + postprocess ----------------
__global__ __launch_bounds__(256) void k_head(const float* __restrict__ partialM,
        const float* __restrict__ b1, const float* __restrict__ W2,
        const float* __restrict__ b2, const float* __restrict__ A,
        const float* __restrict__ x_mod, float* __restrict__ outp) {
    int b = blockIdx.x;
    int tid = threadIdx.x;
    __shared__ float hid[MLP_HID];
    __shared__ float oacc[OUTD][2];
    __shared__ float o[OUTD], gt[M], vv[V], pfc[M], qfc[M];

    for (int c = tid; c < MLP_HID; c += 256) {
        float s = b1[c];
#pragma unroll
        for (int z = 0; z < 8; ++z) s += partialM[((size_t)z * 256 + b) * MLP_HID + c];
        hid[c] = fmaxf(s, 0.f);
    }
    __syncthreads();

    {
        int col = tid >> 1, half = tid & 1;
        if (col < OUTD) {
            float acc = 0.f;
            int k0 = half * 512;
            const float* w = W2 + (size_t)k0 * OUTD + col;
#pragma unroll 4
            for (int k = 0; k < 512; ++k) acc += hid[k0 + k] * w[(size_t)k * OUTD];
            oacc[col][half] = acc;
        }
    }
    __syncthreads();
    if (tid < OUTD) o[tid] = b2[tid] + oacc[tid][0] + oacc[tid][1];
    __syncthreads();

    if (tid < M) {
        float g = (tid < M - NSW) ? 1.0f : sigmoidf(o[M + V + (tid - (M - NSW))]);
        gt[tid] = g;
        pfc[tid] = g * o[tid];
    }
    if (tid < V) vv[tid] = (tid == 0) ? 1.0f : o[M + tid];
    __syncthreads();

    if (tid < M) {
        float acc = 0.f;
        for (int x = 0; x < V; ++x) acc += vv[x] * A[x * M + tid];
        qfc[tid] = gt[tid] * acc;
    }
    __syncthreads();

    float* zb = outp + (size_t)b * ZDIM;
    if (tid < M) zb[tid] = pfc[tid];
    if (tid < V) zb[M + tid] = vv[tid];
    if (tid < M) zb[M + V + tid] = gt[tid];

    float* zcb = outp + (size_t)B * ZDIM + (size_t)b * ZCDIM;
    if (tid < M) zcb[tid] = qfc[tid];
    if (tid < V) {
        float accp = 0.f, accq = 0.f;
        for (int m = 0; m < M; ++m) {
            float a = A[tid * M + m];
            accp += a * pfc[m];
            accq += a * qfc[m];
        }
        zcb[M + tid]     = x_mod[(size_t)(b * V + tid) * FIN + 0] + accp;
        zcb[M + V + tid] = x_mod[(size_t)(b * V + tid) * FIN + 1] + accq;
    }
}

extern "C" void kernel_launch(void* const* d_in, const int* in_sizes, int n_in,
                              void* d_out, int out_size, void* d_ws, size_t ws_size,
                              hipStream_t stream) {
    const float* x_mod = (const float*)d_in[0];
    const int*   ei    = (const int*)d_in[1];
    const int*   si    = (const int*)d_in[2];
    const float* A     = (const float*)d_in[3];
    const float* embed = (const float*)d_in[4];
    const float* WU0   = (const float*)d_in[5];
    const float* WV0   = (const float*)d_in[6];
    const float* WA0   = (const float*)d_in[7];
    const float* WB0   = (const float*)d_in[8];
    const float* WC0   = (const float*)d_in[9];
    const float* WU1   = (const float*)d_in[10];
    const float* WV1   = (const float*)d_in[11];
    const float* WA1   = (const float*)d_in[12];
    const float* WB1   = (const float*)d_in[13];
    const float* WC1   = (const float*)d_in[14];
    const float* W1    = (const float*)d_in[15];
    const float* b1    = (const float*)d_in[16];
    const float* W2    = (const float*)d_in[17];
    const float* b2    = (const float*)d_in[18];
    float* out = (float*)d_out;

    // Workspace layout (byte offsets), total ~37.6 MB (ws_size ~256 MB)
    char* ws = (char*)d_ws;
    unsigned short* W1t      = (unsigned short*)(ws + 0);          // 1024*6656*2 = 13,631,488
    unsigned short* Wt512    = (unsigned short*)(ws + 13631488);   // 512*128*2   =    131,072
    unsigned short* UVBCb    = (unsigned short*)(ws + 13762560);   // 8000*512*2  =  8,192,000
    unsigned short* x1b      = (unsigned short*)(ws + 21954560);   // 8000*128*2  =  2,048,000
    unsigned short* e0rb     = (unsigned short*)(ws + 24002560);   // 2400*128*2  =    614,400
    float*          sA1      = (float*)(ws + 24616960);            // 2400*128*4  =  1,228,800
    unsigned short* Abf      = (unsigned short*)(ws + 25845760);   // 256*6656*2  =  3,407,872 (rows >=200 unused)
    float*          partialM = (float*)(ws + 29253632);            // 8*256*1024*4=  8,388,608

    // 1. weight prep (W1 transpose->bf16, layer-1 weight pack)
    k_prep<<<dim3(209, 32), 256, 0, stream>>>(W1, WU1, WV1, WB1, WC1, W1t, Wt512);
    // 2. fused layer 0 (proj + message passing + sA1 matvec)
    k_l0<<<B, 512, 0, stream>>>(x_mod, ei, si, embed, WU0, WV0, WB0, WC0, WA0, WA1,
                                x1b, e0rb, sA1);
    // 3. layer-1 projections: (8000x128) @ (128x512) -> UVBCb bf16
    k_gemm<1><<<dim3(8, 125, 1), 256, 0, stream>>>(x1b, Wt512, UVBCb, H, 4, 512);
    // 4. layer-1 combine -> Abf (MLP input, bf16)
    k_comb1<<<B, 512, 0, stream>>>(ei, si, sA1, UVBCb, x1b, e0rb, Abf);
    // 5. MLP hidden: (256x6656) @ (6656x1024), split-K=8 -> partialM
    k_gemm<2><<<dim3(16, 4, 8), 256, 0, stream>>>(Abf, W1t, partialM, MLP_IN, 26, MLP_HID);
    // 6. fused head: reduce + bias/relu + W2 GEMV + graph postprocess
    k_head<<<B, 256, 0, stream>>>(partialM, b1, W2, b2, A, x_mod, out);
}

// Round 5
// 71.182 us; speedup vs baseline: 1.3487x; 1.3487x over previous
//
#include <hip/hip_runtime.h>
#include <math.h>

// Problem constants
#define B       200
#define V       40
#define FIN     16
#define H       128
#define NSW     12
#define NE      40
#define M       52      // NE + NSW
#define MLP_HID 1024
#define OUTD    104     // M + V + NSW
#define MLP_IN  6656    // (NSW + V) * H
#define ZDIM    144
#define ZCDIM   132
#define NCH     13      // MLP split-K chunks

typedef __attribute__((ext_vector_type(8))) short bf16x8;
typedef __attribute__((ext_vector_type(4))) float f32x4;

__device__ __forceinline__ float sigmoidf(float x) {
    return 1.0f / (1.0f + expf(-x));
}
__device__ __forceinline__ unsigned short f2b(float x) {  // fp32 -> bf16 RNE
    unsigned int u = __float_as_uint(x);
    u += 0x7fffu + ((u >> 16) & 1u);
    return (unsigned short)(u >> 16);
}
__device__ __forceinline__ float b2f(unsigned short s) {
    return __uint_as_float(((unsigned int)s) << 16);
}

// ---------------- weight prep (merged) ----------------
// x<208: W1 (6656x1024 f32) -> W1t (1024x6656 bf16), 32x32 LDS tiles
// x==208: {WU1,WV1,WB1,WC1} -> Wt512[col][k] bf16
// x==209: W2 (1024x104) -> W2t[col][k] bf16 (cols 104..127 zero)
__global__ __launch_bounds__(256) void k_prep(const float* __restrict__ W1,
        const float* __restrict__ WU, const float* __restrict__ WV,
        const float* __restrict__ WB, const float* __restrict__ WC,
        const float* __restrict__ W2,
        unsigned short* __restrict__ W1t, unsigned short* __restrict__ Wt512,
        unsigned short* __restrict__ W2t) {
    int tid = threadIdx.x;
    if (blockIdx.x < 208) {
        int k0 = blockIdx.x * 32, n0 = blockIdx.y * 32;
        __shared__ float tile[32][33];
        int c = tid & 31, r8 = tid >> 5;
#pragma unroll
        for (int i = 0; i < 4; ++i) {
            int r = r8 + i * 8;
            tile[r][c] = W1[(size_t)(k0 + r) * MLP_HID + n0 + c];
        }
        __syncthreads();
#pragma unroll
        for (int i = 0; i < 4; ++i) {
            int rr = r8 + i * 8;
            W1t[(size_t)(n0 + rr) * MLP_IN + k0 + c] = f2b(tile[c][rr]);
        }
    } else if (blockIdx.x == 208) {
        int base = (blockIdx.y * 256 + tid) * 8;
#pragma unroll
        for (int i = 0; i < 8; ++i) {
            int o = base + i;                 // < 512*128
            int col = o >> 7, f = o & 127;
            int m = col >> 7, h = col & 127;
            const float* Ws = (m == 0) ? WU : (m == 1) ? WV : (m == 2) ? WB : WC;
            Wt512[o] = f2b(Ws[f * H + h]);
        }
    } else {
        // W2t: 128*1024 elems; o = col*1024 + k
        for (int o = blockIdx.y * 4096 + tid; o < blockIdx.y * 4096 + 4096; o += 256) {
            int col = o >> 10, k = o & 1023;
            W2t[o] = (col < OUTD) ? f2b(W2[(size_t)k * OUTD + col]) : (unsigned short)0;
        }
    }
}

// ---------------- fused layer 0: proj0 + comb0 + sA1 ----------------
__global__ __launch_bounds__(512) void k_l0(const float* __restrict__ x,
        const int* __restrict__ ei, const int* __restrict__ si,
        const float* __restrict__ embed,
        const float* __restrict__ WU0, const float* __restrict__ WV0,
        const float* __restrict__ WB0, const float* __restrict__ WC0,
        const float* __restrict__ WA0, const float* __restrict__ WA1,
        unsigned short* __restrict__ x1b, unsigned short* __restrict__ e0rb,
        float* __restrict__ sA1) {
    int b = blockIdx.x;
    int tid = threadIdx.x;
    __shared__ unsigned short uvbc[V * 512];   // 40 KB
    __shared__ float msg[4][V][H];             // 80 KB
    __shared__ float xs[V * FIN];
    __shared__ unsigned short e0s[NSW * H];

    for (int i = tid; i < V * FIN; i += 512) xs[i] = x[(size_t)b * V * FIN + i];
    __syncthreads();

    {
        int m = tid >> 7, hh = tid & 127;
        const float* Wm = (m == 0) ? WU0 : (m == 1) ? WV0 : (m == 2) ? WB0 : WC0;
        float w[FIN];
#pragma unroll
        for (int f = 0; f < FIN; ++f) w[f] = Wm[f * H + hh];
        for (int r = 0; r < V; ++r) {
            float acc = 0.f;
#pragma unroll
            for (int f = 0; f < FIN; ++f) acc += xs[r * FIN + f] * w[f];
            uvbc[r * 512 + tid] = f2b(acc);
        }
    }

    int h = tid & 127, sub = tid >> 7;
    for (int i = 0; i < V; ++i) msg[sub][i][h] = 0.f;
    __syncthreads();

    float sA0 = 0.f;
#pragma unroll
    for (int f = 0; f < FIN; ++f) sA0 += embed[FIN + f] * WA0[f * H + h];

    for (int e = sub * 10; e < sub * 10 + 10; ++e) {
        int i = ei[e], j = ei[NE + e];
        msg[sub][i][h] += b2f(uvbc[j * 512 + 128 + h]);
        msg[sub][j][h] += b2f(uvbc[i * 512 + 128 + h]);
    }
    for (int k = sub * 3; k < sub * 3 + 3; ++k) {
        int i = si[k], j = si[NSW + k];
        float e0 = sA0 + b2f(uvbc[i * 512 + 256 + h]) + b2f(uvbc[j * 512 + 384 + h]);
        float g = sigmoidf(e0);
        msg[sub][i][h] += g * b2f(uvbc[j * 512 + 128 + h]);
        unsigned short r = f2b(fmaxf(e0, 0.f));
        e0s[k * H + h] = r;
        e0rb[(size_t)(b * NSW + k) * H + h] = r;
    }
    __syncthreads();

    for (int i = sub * 10; i < sub * 10 + 10; ++i) {
        float v = b2f(uvbc[i * 512 + h]) + msg[0][i][h] + msg[1][i][h] + msg[2][i][h] + msg[3][i][h];
        x1b[(size_t)(b * V + i) * H + h] = f2b(fmaxf(v, 0.f));
    }

    for (int o = tid; o < NSW * H; o += 512) {
        int k = o >> 7, hh = o & 127;
        float acc = 0.f;
#pragma unroll 8
        for (int f = 0; f < H; ++f) acc += b2f(e0s[k * H + f]) * WA1[f * H + hh];
        sA1[(size_t)b * NSW * H + o] = acc;
    }
}

// ---------------- layer-1 combine ----------------
__global__ __launch_bounds__(512) void k_comb1(const int* __restrict__ ei,
        const int* __restrict__ si, const float* __restrict__ sA1,
        const unsigned short* __restrict__ uvbc_g, const unsigned short* __restrict__ x1b,
        const unsigned short* __restrict__ e0rb, unsigned short* __restrict__ Abf) {
    int b = blockIdx.x;
    int tid = threadIdx.x;
    int h = tid & 127, sub = tid >> 7;
    __shared__ float msg[4][V][H];
    for (int i = 0; i < V; ++i) msg[sub][i][h] = 0.f;

    const unsigned short* base = uvbc_g + (size_t)b * V * 512;
    for (int e = sub * 10; e < sub * 10 + 10; ++e) {
        int i = ei[e], j = ei[NE + e];
        msg[sub][i][h] += b2f(base[j * 512 + 128 + h]);
        msg[sub][j][h] += b2f(base[i * 512 + 128 + h]);
    }
    for (int k = sub * 3; k < sub * 3 + 3; ++k) {
        int i = si[k], j = si[NSW + k];
        float e1 = sA1[(size_t)(b * NSW + k) * H + h]
                 + b2f(base[i * 512 + 256 + h]) + b2f(base[j * 512 + 384 + h]);
        float g = sigmoidf(e1);
        msg[sub][i][h] += g * b2f(base[j * 512 + 128 + h]);
        float s1 = b2f(e0rb[(size_t)(b * NSW + k) * H + h]);
        Abf[(size_t)b * MLP_IN + k * H + h] = f2b(s1 + fmaxf(e1, 0.f));
    }
    __syncthreads();
    for (int i = sub * 10; i < sub * 10 + 10; ++i) {
        float xh = b2f(base[i * 512 + h]) + msg[0][i][h] + msg[1][i][h] + msg[2][i][h] + msg[3][i][h];
        float x2 = b2f(x1b[(size_t)(b * V + i) * H + h]) + fmaxf(xh, 0.f);
        Abf[(size_t)b * MLP_IN + NSW * H + i * H + h] = f2b(x2);
    }
}

// ---------------- generic bf16 MFMA GEMM ----------------
// C[MxN] = A[MxK](bf16,rowmajor) @ Bt[NxK](bf16,rowmajor)^T
// MODE 1: write bf16 C.  MODE 2: write f32 split-K partial[z].
template<int MODE>
__global__ __launch_bounds__(256) void k_gemm(const unsigned short* __restrict__ A,
        const unsigned short* __restrict__ Bt, void* __restrict__ Cout,
        int K, int nk, int ldc) {
    int tid = threadIdx.x;
    int lane = tid & 63, wv = tid >> 6;
    int wr = (wv >> 1) * 32, wc = (wv & 1) * 32;
    int n0 = blockIdx.x * 64, m0 = blockIdx.y * 64;
    size_t kbase = (size_t)blockIdx.z * nk * 32;

    __shared__ __align__(16) unsigned short a_lds[64 * 40];
    __shared__ __align__(16) unsigned short b_lds[64 * 40];

    f32x4 acc00 = {0,0,0,0}, acc01 = {0,0,0,0}, acc10 = {0,0,0,0}, acc11 = {0,0,0,0};

    int srow = tid >> 2, sseg = tid & 3;
    const int4* gA = (const int4*)(A + (size_t)(m0 + srow) * K + kbase + sseg * 8);
    const int4* gB = (const int4*)(Bt + (size_t)(n0 + srow) * K + kbase + sseg * 8);
    int lws = srow * 40 + sseg * 8;

    int a_off = (wr + (lane & 15)) * 40 + (lane >> 4) * 8;
    int b_off = (wc + (lane & 15)) * 40 + (lane >> 4) * 8;

    int4 ra = gA[0], rb = gB[0];
    for (int kk = 0; kk < nk; ++kk) {
        *(int4*)&a_lds[lws] = ra;
        *(int4*)&b_lds[lws] = rb;
        __syncthreads();
        if (kk + 1 < nk) { ra = gA[(kk + 1) * 4]; rb = gB[(kk + 1) * 4]; }
        bf16x8 a0 = *(const bf16x8*)&a_lds[a_off];
        bf16x8 a1 = *(const bf16x8*)&a_lds[a_off + 16 * 40];
        bf16x8 b0 = *(const bf16x8*)&b_lds[b_off];
        bf16x8 b1 = *(const bf16x8*)&b_lds[b_off + 16 * 40];
        acc00 = __builtin_amdgcn_mfma_f32_16x16x32_bf16(a0, b0, acc00, 0, 0, 0);
        acc01 = __builtin_amdgcn_mfma_f32_16x16x32_bf16(a0, b1, acc01, 0, 0, 0);
        acc10 = __builtin_amdgcn_mfma_f32_16x16x32_bf16(a1, b0, acc10, 0, 0, 0);
        acc11 = __builtin_amdgcn_mfma_f32_16x16x32_bf16(a1, b1, acc11, 0, 0, 0);
        __syncthreads();
    }

    int crow = (lane >> 4) * 4;
    int ccol = lane & 15;
    int row0 = m0 + wr + crow, row1 = row0 + 16;
    int col0 = n0 + wc + ccol, col1 = col0 + 16;
    if (MODE == 1) {
        unsigned short* dst = (unsigned short*)Cout;
#pragma unroll
        for (int r = 0; r < 4; ++r) {
            dst[(size_t)(row0 + r) * ldc + col0] = f2b(acc00[r]);
            dst[(size_t)(row0 + r) * ldc + col1] = f2b(acc01[r]);
            dst[(size_t)(row1 + r) * ldc + col0] = f2b(acc10[r]);
            dst[(size_t)(row1 + r) * ldc + col1] = f2b(acc11[r]);
        }
    } else {
        float* dst = (float*)Cout + (size_t)blockIdx.z * (gridDim.y * 64) * ldc;
#pragma unroll
        for (int r = 0; r < 4; ++r) {
            dst[(size_t)(row0 + r) * ldc + col0] = acc00[r];
            dst[(size_t)(row0 + r) * ldc + col1] = acc01[r];
            dst[(size_t)(row1 + r) * ldc + col0] = acc10[r];
            dst[(size_t)(row1 + r) * ldc + col1] = acc11[r];
        }
    }
}

// reduce MLP split-K partials + bias + relu -> bf16 hidden
__global__ void k_mred(const float* __restrict__ partial, const float* __restrict__ b1,
                       unsigned short* __restrict__ hiddenb) {
    int i = blockIdx.x * 256 + threadIdx.x;   // < 256*1024
    float s = b1[i & (MLP_HID - 1)];
#pragma unroll
    for (int z = 0; z < NCH; ++z) s += partial[(size_t)z * 256 * MLP_HID + i];
    hiddenb[i] = f2b(fmaxf(s, 0.f));
}

// ---------------- finalize: reduce head partials + postprocess ----------------
__global__ __launch_bounds__(128) void k_fin(const float* __restrict__ partial2,
        const float* __restrict__ b2, const float* __restrict__ A,
        const float* __restrict__ x_mod, float* __restrict__ outp) {
    int b = blockIdx.x;
    int tid = threadIdx.x;
    __shared__ float o[OUTD];
    __shared__ float gt[M], vv[V], pfc[M], qfc[M];

    if (tid < OUTD) {
        float s = b2[tid];
#pragma unroll
        for (int z = 0; z < 4; ++z) s += partial2[(size_t)z * 256 * 128 + b * 128 + tid];
        o[tid] = s;
    }
    __syncthreads();

    if (tid < M) {
        float g = (tid < M - NSW) ? 1.0f : sigmoidf(o[M + V + (tid - (M - NSW))]);
        gt[tid] = g;
        pfc[tid] = g * o[tid];
    }
    if (tid < V) vv[tid] = (tid == 0) ? 1.0f : o[M + tid];
    __syncthreads();

    if (tid < M) {
        float acc = 0.f;
        for (int x = 0; x < V; ++x) acc += vv[x] * A[x * M + tid];
        qfc[tid] = gt[tid] * acc;
    }
    __syncthreads();

    float* zb = outp + (size_t)b * ZDIM;
    if (tid < M) zb[tid] = pfc[tid];
    if (tid < V) zb[M + tid] = vv[tid];
    if (tid < M) zb[M + V + tid] = gt[tid];

    float* zcb = outp + (size_t)B * ZDIM + (size_t)b * ZCDIM;
    if (tid < M) zcb[tid] = qfc[tid];
    if (tid < V) {
        float accp = 0.f, accq = 0.f;
        for (int m = 0; m < M; ++m) {
            float a = A[tid * M + m];
            accp += a * pfc[m];
            accq += a * qfc[m];
        }
        zcb[M + tid]     = x_mod[(size_t)(b * V + tid) * FIN + 0] + accp;
        zcb[M + V + tid] = x_mod[(size_t)(b * V + tid) * FIN + 1] + accq;
    }
}

extern "C" void kernel_launch(void* const* d_in, const int* in_sizes, int n_in,
                              void* d_out, int out_size, void* d_ws, size_t ws_size,
                              hipStream_t stream) {
    const float* x_mod = (const float*)d_in[0];
    const int*   ei    = (const int*)d_in[1];
    const int*   si    = (const int*)d_in[2];
    const float* A     = (const float*)d_in[3];
    const float* embed = (const float*)d_in[4];
    const float* WU0   = (const float*)d_in[5];
    const float* WV0   = (const float*)d_in[6];
    const float* WA0   = (const float*)d_in[7];
    const float* WB0   = (const float*)d_in[8];
    const float* WC0   = (const float*)d_in[9];
    const float* WU1   = (const float*)d_in[10];
    const float* WV1   = (const float*)d_in[11];
    const float* WA1   = (const float*)d_in[12];
    const float* WB1   = (const float*)d_in[13];
    const float* WC1   = (const float*)d_in[14];
    const float* W1    = (const float*)d_in[15];
    const float* b1    = (const float*)d_in[16];
    const float* W2    = (const float*)d_in[17];
    const float* b2    = (const float*)d_in[18];
    float* out = (float*)d_out;

    // Workspace layout (byte offsets), total ~44 MB (ws_size ~256 MB)
    char* ws = (char*)d_ws;
    unsigned short* W1t      = (unsigned short*)(ws + 0);          // 13,631,488
    unsigned short* Wt512    = (unsigned short*)(ws + 13631488);   //    131,072
    unsigned short* W2t      = (unsigned short*)(ws + 13762560);   //    262,144
    unsigned short* UVBCb    = (unsigned short*)(ws + 14024704);   //  8,192,000
    unsigned short* x1b      = (unsigned short*)(ws + 22216704);   //  2,048,000
    unsigned short* e0rb     = (unsigned short*)(ws + 24264704);   //    614,400
    float*          sA1      = (float*)(ws + 24879104);            //  1,228,800
    unsigned short* Abf      = (unsigned short*)(ws + 26107904);   //  3,407,872
    float*          partialM = (float*)(ws + 29515776);            // 13,631,488
    unsigned short* hiddenb  = (unsigned short*)(ws + 43147264);   //    524,288
    float*          partial2 = (float*)(ws + 43671552);            //    524,288

    // 1. weight prep (W1 transpose, layer-1 pack, W2 transpose)
    k_prep<<<dim3(210, 32), 256, 0, stream>>>(W1, WU1, WV1, WB1, WC1, W2, W1t, Wt512, W2t);
    // 2. fused layer 0
    k_l0<<<B, 512, 0, stream>>>(x_mod, ei, si, embed, WU0, WV0, WB0, WC0, WA0, WA1,
                                x1b, e0rb, sA1);
    // 3. layer-1 projections: (8000x128) @ (128x512) -> UVBCb bf16
    k_gemm<1><<<dim3(8, 125, 1), 256, 0, stream>>>(x1b, Wt512, UVBCb, H, 4, 512);
    // 4. layer-1 combine -> Abf (MLP input, bf16)
    k_comb1<<<B, 512, 0, stream>>>(ei, si, sA1, UVBCb, x1b, e0rb, Abf);
    // 5. MLP hidden: (256x6656) @ (6656x1024), split-K=13 -> partialM
    k_gemm<2><<<dim3(16, 4, NCH), 256, 0, stream>>>(Abf, W1t, partialM, MLP_IN, 16, MLP_HID);
    // 6. reduce + bias + relu -> hiddenb bf16
    k_mred<<<256 * MLP_HID / 256, 256, 0, stream>>>(partialM, b1, hiddenb);
    // 7. head GEMM: (256x1024) @ (1024x128), split-K=4 -> partial2
    k_gemm<2><<<dim3(2, 4, 4), 256, 0, stream>>>(hiddenb, W2t, partial2, MLP_HID, 8, 128);
    // 8. finalize: reduce + graph postprocess
    k_fin<<<B, 128, 0, stream>>>(partial2, b2, A, x_mod, out);
}

// Round 6
// 66.219 us; speedup vs baseline: 1.4498x; 1.0749x over previous
//
#include <hip/hip_runtime.h>
#include <math.h>

// Problem constants
#define B       200
#define V       40
#define FIN     16
#define H       128
#define NSW     12
#define NE      40
#define M       52      // NE + NSW
#define MLP_HID 1024
#define OUTD    104     // M + V + NSW
#define MLP_IN  6656    // (NSW + V) * H
#define ZDIM    144
#define ZCDIM   132
#define NCH     13      // MLP split-K chunks
#define X1LD    136     // x1 LDS row stride (shorts): 128 + 8 pad -> 272B, 8-bank spread

typedef __attribute__((ext_vector_type(8))) short bf16x8;
typedef __attribute__((ext_vector_type(4))) float f32x4;

__device__ __forceinline__ float sigmoidf(float x) {
    return 1.0f / (1.0f + expf(-x));
}
__device__ __forceinline__ unsigned short f2b(float x) {  // fp32 -> bf16 RNE
    unsigned int u = __float_as_uint(x);
    u += 0x7fffu + ((u >> 16) & 1u);
    return (unsigned short)(u >> 16);
}
__device__ __forceinline__ float b2f(unsigned short s) {
    return __uint_as_float(((unsigned int)s) << 16);
}

// ---------------- weight prep (merged) ----------------
// x<208: W1 (6656x1024 f32) -> W1t (1024x6656 bf16), 32x32 LDS tiles
// x==208: {WU1,WV1,WB1,WC1} -> Wt512[col][k] bf16
// x==209: W2 (1024x104) -> W2t[col][k] bf16 (cols 104..127 zero)
__global__ __launch_bounds__(256) void k_prep(const float* __restrict__ W1,
        const float* __restrict__ WU, const float* __restrict__ WV,
        const float* __restrict__ WB, const float* __restrict__ WC,
        const float* __restrict__ W2,
        unsigned short* __restrict__ W1t, unsigned short* __restrict__ Wt512,
        unsigned short* __restrict__ W2t) {
    int tid = threadIdx.x;
    if (blockIdx.x < 208) {
        int k0 = blockIdx.x * 32, n0 = blockIdx.y * 32;
        __shared__ float tile[32][33];
        int c = tid & 31, r8 = tid >> 5;
#pragma unroll
        for (int i = 0; i < 4; ++i) {
            int r = r8 + i * 8;
            tile[r][c] = W1[(size_t)(k0 + r) * MLP_HID + n0 + c];
        }
        __syncthreads();
#pragma unroll
        for (int i = 0; i < 4; ++i) {
            int rr = r8 + i * 8;
            W1t[(size_t)(n0 + rr) * MLP_IN + k0 + c] = f2b(tile[c][rr]);
        }
    } else if (blockIdx.x == 208) {
        int base = (blockIdx.y * 256 + tid) * 8;
#pragma unroll
        for (int i = 0; i < 8; ++i) {
            int o = base + i;                 // < 512*128
            int col = o >> 7, f = o & 127;
            int m = col >> 7, h = col & 127;
            const float* Ws = (m == 0) ? WU : (m == 1) ? WV : (m == 2) ? WB : WC;
            Wt512[o] = f2b(Ws[f * H + h]);
        }
    } else {
        for (int o = blockIdx.y * 4096 + tid; o < blockIdx.y * 4096 + 4096; o += 256) {
            int col = o >> 10, k = o & 1023;
            W2t[o] = (col < OUTD) ? f2b(W2[(size_t)k * OUTD + col]) : (unsigned short)0;
        }
    }
}

// ---------------- fully fused GNN: proj0+comb0+sA1+proj1(MFMA)+comb1 ----------------
// one block per batch, 512 threads (8 waves), ~144.5 KB LDS
__global__ __launch_bounds__(512) void k_gnn(const float* __restrict__ x,
        const int* __restrict__ ei, const int* __restrict__ si,
        const float* __restrict__ embed,
        const float* __restrict__ WU0, const float* __restrict__ WV0,
        const float* __restrict__ WB0, const float* __restrict__ WC0,
        const float* __restrict__ WA0, const float* __restrict__ WA1,
        const unsigned short* __restrict__ Wt512,
        unsigned short* __restrict__ Abf) {
    int b = blockIdx.x;
    int tid = threadIdx.x;
    __shared__ unsigned short uvbc[V * 512];     // 40 KB  [row][m*128+h] (L0, then L1)
    __shared__ float msg[4][V][H];               // 80 KB
    __shared__ unsigned short x1l[48 * X1LD];    // 13 KB  x1 bf16, padded rows/stride
    __shared__ unsigned short e0s[NSW * H];      // 3 KB   relu(e0) bf16
    __shared__ float xs[V * FIN];                // 2.5 KB
    __shared__ float sA1l[NSW * H];              // 6 KB

    // ---- load x ----
    for (int i = tid; i < V * FIN; i += 512) xs[i] = x[(size_t)b * V * FIN + i];
    __syncthreads();

    int h = tid & 127, sub = tid >> 7;

    // ---- phase A: proj0 (thread owns col m*128+h) ----
    {
        int m = sub;
        const float* Wm = (m == 0) ? WU0 : (m == 1) ? WV0 : (m == 2) ? WB0 : WC0;
        float w[FIN];
#pragma unroll
        for (int f = 0; f < FIN; ++f) w[f] = Wm[f * H + h];
        for (int r = 0; r < V; ++r) {
            float acc = 0.f;
#pragma unroll
            for (int f = 0; f < FIN; ++f) acc += xs[r * FIN + f] * w[f];
            uvbc[r * 512 + tid] = f2b(acc);
        }
    }
    for (int i = 0; i < V; ++i) msg[sub][i][h] = 0.f;   // own column, no race
    __syncthreads();   // uvbc(L0) ready

    // ---- phase A2: comb0 message passing ----
    float sA0 = 0.f;
#pragma unroll
    for (int f = 0; f < FIN; ++f) sA0 += embed[FIN + f] * WA0[f * H + h];

    for (int e = sub * 10; e < sub * 10 + 10; ++e) {
        int i = ei[e], j = ei[NE + e];
        msg[sub][i][h] += b2f(uvbc[j * 512 + 128 + h]);   // Vx[j]
        msg[sub][j][h] += b2f(uvbc[i * 512 + 128 + h]);
    }
    for (int k = sub * 3; k < sub * 3 + 3; ++k) {
        int i = si[k], j = si[NSW + k];
        float e0 = sA0 + b2f(uvbc[i * 512 + 256 + h]) + b2f(uvbc[j * 512 + 384 + h]);
        float g = sigmoidf(e0);
        msg[sub][i][h] += g * b2f(uvbc[j * 512 + 128 + h]);
        e0s[k * H + h] = f2b(fmaxf(e0, 0.f));
    }
    __syncthreads();   // msg + e0s ready

    // ---- phase A3: x1 -> LDS (padded), zero pad rows, sA1 matvec ----
    for (int i = sub * 10; i < sub * 10 + 10; ++i) {
        float v = b2f(uvbc[i * 512 + h]) + msg[0][i][h] + msg[1][i][h] + msg[2][i][h] + msg[3][i][h];
        x1l[i * X1LD + h] = f2b(fmaxf(v, 0.f));
    }
    for (int i = 40 + sub; i < 48; i += 4) x1l[i * X1LD + h] = 0;
    for (int o = tid; o < NSW * H; o += 512) {
        int k = o >> 7, hh = o & 127;
        float acc = 0.f;
#pragma unroll 8
        for (int f = 0; f < H; ++f) acc += b2f(e0s[k * H + f]) * WA1[f * H + hh];
        sA1l[o] = acc;
    }
    __syncthreads();   // x1l + sA1l ready; uvbc(L0) dead

    // ---- phase B: proj1 MFMA — uvbc(L1)[40x512] = x1[48x128] @ Wt512^T ----
    {
        int lane = tid & 63, wvid = tid >> 6;   // 8 waves x 64 cols
        int n0w = wvid * 64;
        int lr = lane & 15, lk = lane >> 4;
        f32x4 acc[3][4];
#pragma unroll
        for (int rf = 0; rf < 3; ++rf)
#pragma unroll
            for (int cf = 0; cf < 4; ++cf) acc[rf][cf] = (f32x4){0.f, 0.f, 0.f, 0.f};

#pragma unroll
        for (int kk = 0; kk < 4; ++kk) {
            int kseg = kk * 32 + lk * 8;
            bf16x8 af0 = *(const bf16x8*)&x1l[(0 * 16 + lr) * X1LD + kseg];
            bf16x8 af1 = *(const bf16x8*)&x1l[(1 * 16 + lr) * X1LD + kseg];
            bf16x8 af2 = *(const bf16x8*)&x1l[(2 * 16 + lr) * X1LD + kseg];
#pragma unroll
            for (int cf = 0; cf < 4; ++cf) {
                int col = n0w + cf * 16 + lr;
                bf16x8 bf = *(const bf16x8*)&Wt512[col * 128 + kseg];
                acc[0][cf] = __builtin_amdgcn_mfma_f32_16x16x32_bf16(af0, bf, acc[0][cf], 0, 0, 0);
                acc[1][cf] = __builtin_amdgcn_mfma_f32_16x16x32_bf16(af1, bf, acc[1][cf], 0, 0, 0);
                acc[2][cf] = __builtin_amdgcn_mfma_f32_16x16x32_bf16(af2, bf, acc[2][cf], 0, 0, 0);
            }
        }
        // write uvbc(L1): row = rf*16 + lk*4 + r (discard rows >= 40), col = n0w+cf*16+lr
#pragma unroll
        for (int rf = 0; rf < 3; ++rf)
#pragma unroll
            for (int cf = 0; cf < 4; ++cf)
#pragma unroll
                for (int r = 0; r < 4; ++r) {
                    int row = rf * 16 + lk * 4 + r;
                    if (row < V) uvbc[row * 512 + n0w + cf * 16 + lr] = f2b(acc[rf][cf][r]);
                }
    }
    for (int i = 0; i < V; ++i) msg[sub][i][h] = 0.f;   // re-zero own column
    __syncthreads();   // uvbc(L1) ready

    // ---- phase C: comb1 -> Abf ----
    for (int e = sub * 10; e < sub * 10 + 10; ++e) {
        int i = ei[e], j = ei[NE + e];
        msg[sub][i][h] += b2f(uvbc[j * 512 + 128 + h]);
        msg[sub][j][h] += b2f(uvbc[i * 512 + 128 + h]);
    }
    for (int k = sub * 3; k < sub * 3 + 3; ++k) {
        int i = si[k], j = si[NSW + k];
        float e1 = sA1l[k * H + h] + b2f(uvbc[i * 512 + 256 + h]) + b2f(uvbc[j * 512 + 384 + h]);
        float g = sigmoidf(e1);
        msg[sub][i][h] += g * b2f(uvbc[j * 512 + 128 + h]);
        float s1 = b2f(e0s[k * H + h]);
        Abf[(size_t)b * MLP_IN + k * H + h] = f2b(s1 + fmaxf(e1, 0.f));  // s2 at switch
    }
    __syncthreads();
    for (int i = sub * 10; i < sub * 10 + 10; ++i) {
        float xh = b2f(uvbc[i * 512 + h]) + msg[0][i][h] + msg[1][i][h] + msg[2][i][h] + msg[3][i][h];
        float x2 = b2f(x1l[i * X1LD + h]) + fmaxf(xh, 0.f);   // residual
        Abf[(size_t)b * MLP_IN + NSW * H + i * H + h] = f2b(x2);
    }
}

// ---------------- generic bf16 MFMA GEMM ----------------
// C[MxN] = A[MxK](bf16,rowmajor) @ Bt[NxK](bf16,rowmajor)^T
// MODE 1: write bf16 C.  MODE 2: write f32 split-K partial[z].
template<int MODE>
__global__ __launch_bounds__(256) void k_gemm(const unsigned short* __restrict__ A,
        const unsigned short* __restrict__ Bt, void* __restrict__ Cout,
        int K, int nk, int ldc) {
    int tid = threadIdx.x;
    int lane = tid & 63, wv = tid >> 6;
    int wr = (wv >> 1) * 32, wc = (wv & 1) * 32;
    int n0 = blockIdx.x * 64, m0 = blockIdx.y * 64;
    size_t kbase = (size_t)blockIdx.z * nk * 32;

    __shared__ __align__(16) unsigned short a_lds[64 * 40];
    __shared__ __align__(16) unsigned short b_lds[64 * 40];

    f32x4 acc00 = {0,0,0,0}, acc01 = {0,0,0,0}, acc10 = {0,0,0,0}, acc11 = {0,0,0,0};

    int srow = tid >> 2, sseg = tid & 3;
    const int4* gA = (const int4*)(A + (size_t)(m0 + srow) * K + kbase + sseg * 8);
    const int4* gB = (const int4*)(Bt + (size_t)(n0 + srow) * K + kbase + sseg * 8);
    int lws = srow * 40 + sseg * 8;

    int a_off = (wr + (lane & 15)) * 40 + (lane >> 4) * 8;
    int b_off = (wc + (lane & 15)) * 40 + (lane >> 4) * 8;

    int4 ra = gA[0], rb = gB[0];
    for (int kk = 0; kk < nk; ++kk) {
        *(int4*)&a_lds[lws] = ra;
        *(int4*)&b_lds[lws] = rb;
        __syncthreads();
        if (kk + 1 < nk) { ra = gA[(kk + 1) * 4]; rb = gB[(kk + 1) * 4]; }
        bf16x8 a0 = *(const bf16x8*)&a_lds[a_off];
        bf16x8 a1 = *(const bf16x8*)&a_lds[a_off + 16 * 40];
        bf16x8 b0 = *(const bf16x8*)&b_lds[b_off];
        bf16x8 b1 = *(const bf16x8*)&b_lds[b_off + 16 * 40];
        acc00 = __builtin_amdgcn_mfma_f32_16x16x32_bf16(a0, b0, acc00, 0, 0, 0);
        acc01 = __builtin_amdgcn_mfma_f32_16x16x32_bf16(a0, b1, acc01, 0, 0, 0);
        acc10 = __builtin_amdgcn_mfma_f32_16x16x32_bf16(a1, b0, acc10, 0, 0, 0);
        acc11 = __builtin_amdgcn_mfma_f32_16x16x32_bf16(a1, b1, acc11, 0, 0, 0);
        __syncthreads();
    }

    int crow = (lane >> 4) * 4;
    int ccol = lane & 15;
    int row0 = m0 + wr + crow, row1 = row0 + 16;
    int col0 = n0 + wc + ccol, col1 = col0 + 16;
    if (MODE == 1) {
        unsigned short* dst = (unsigned short*)Cout;
#pragma unroll
        for (int r = 0; r < 4; ++r) {
            dst[(size_t)(row0 + r) * ldc + col0] = f2b(acc00[r]);
            dst[(size_t)(row0 + r) * ldc + col1] = f2b(acc01[r]);
            dst[(size_t)(row1 + r) * ldc + col0] = f2b(acc10[r]);
            dst[(size_t)(row1 + r) * ldc + col1] = f2b(acc11[r]);
        }
    } else {
        float* dst = (float*)Cout + (size_t)blockIdx.z * (gridDim.y * 64) * ldc;
#pragma unroll
        for (int r = 0; r < 4; ++r) {
            dst[(size_t)(row0 + r) * ldc + col0] = acc00[r];
            dst[(size_t)(row0 + r) * ldc + col1] = acc01[r];
            dst[(size_t)(row1 + r) * ldc + col0] = acc10[r];
            dst[(size_t)(row1 + r) * ldc + col1] = acc11[r];
        }
    }
}

// reduce MLP split-K partials + bias + relu -> bf16 hidden
__global__ void k_mred(const float* __restrict__ partial, const float* __restrict__ b1,
                       unsigned short* __restrict__ hiddenb) {
    int i = blockIdx.x * 256 + threadIdx.x;   // < 256*1024
    float s = b1[i & (MLP_HID - 1)];
#pragma unroll
    for (int z = 0; z < NCH; ++z) s += partial[(size_t)z * 256 * MLP_HID + i];
    hiddenb[i] = f2b(fmaxf(s, 0.f));
}

// ---------------- finalize: reduce head partials + postprocess ----------------
__global__ __launch_bounds__(128) void k_fin(const float* __restrict__ partial2,
        const float* __restrict__ b2, const float* __restrict__ A,
        const float* __restrict__ x_mod, float* __restrict__ outp) {
    int b = blockIdx.x;
    int tid = threadIdx.x;
    __shared__ float o[OUTD];
    __shared__ float gt[M], vv[V], pfc[M], qfc[M];

    if (tid < OUTD) {
        float s = b2[tid];
#pragma unroll
        for (int z = 0; z < 4; ++z) s += partial2[(size_t)z * 256 * 128 + b * 128 + tid];
        o[tid] = s;
    }
    __syncthreads();

    if (tid < M) {
        float g = (tid < M - NSW) ? 1.0f : sigmoidf(o[M + V + (tid - (M - NSW))]);
        gt[tid] = g;
        pfc[tid] = g * o[tid];
    }
    if (tid < V) vv[tid] = (tid == 0) ? 1.0f : o[M + tid];
    __syncthreads();

    if (tid < M) {
        float acc = 0.f;
        for (int x = 0; x < V; ++x) acc += vv[x] * A[x * M + tid];
        qfc[tid] = gt[tid] * acc;
    }
    __syncthreads();

    float* zb = outp + (size_t)b * ZDIM;
    if (tid < M) zb[tid] = pfc[tid];
    if (tid < V) zb[M + tid] = vv[tid];
    if (tid < M) zb[M + V + tid] = gt[tid];

    float* zcb = outp + (size_t)B * ZDIM + (size_t)b * ZCDIM;
    if (tid < M) zcb[tid] = qfc[tid];
    if (tid < V) {
        float accp = 0.f, accq = 0.f;
        for (int m = 0; m < M; ++m) {
            float a = A[tid * M + m];
            accp += a * pfc[m];
            accq += a * qfc[m];
        }
        zcb[M + tid]     = x_mod[(size_t)(b * V + tid) * FIN + 0] + accp;
        zcb[M + V + tid] = x_mod[(size_t)(b * V + tid) * FIN + 1] + accq;
    }
}

extern "C" void kernel_launch(void* const* d_in, const int* in_sizes, int n_in,
                              void* d_out, int out_size, void* d_ws, size_t ws_size,
                              hipStream_t stream) {
    const float* x_mod = (const float*)d_in[0];
    const int*   ei    = (const int*)d_in[1];
    const int*   si    = (const int*)d_in[2];
    const float* A     = (const float*)d_in[3];
    const float* embed = (const float*)d_in[4];
    const float* WU0   = (const float*)d_in[5];
    const float* WV0   = (const float*)d_in[6];
    const float* WA0   = (const float*)d_in[7];
    const float* WB0   = (const float*)d_in[8];
    const float* WC0   = (const float*)d_in[9];
    const float* WU1   = (const float*)d_in[10];
    const float* WV1   = (const float*)d_in[11];
    const float* WA1   = (const float*)d_in[12];
    const float* WB1   = (const float*)d_in[13];
    const float* WC1   = (const float*)d_in[14];
    const float* W1    = (const float*)d_in[15];
    const float* b1    = (const float*)d_in[16];
    const float* W2    = (const float*)d_in[17];
    const float* b2    = (const float*)d_in[18];
    float* out = (float*)d_out;

    // Workspace layout (byte offsets), ~32 MB (ws_size ~256 MB)
    char* ws = (char*)d_ws;
    unsigned short* W1t      = (unsigned short*)(ws + 0);          // 13,631,488
    unsigned short* Wt512    = (unsigned short*)(ws + 13631488);   //    131,072
    unsigned short* W2t      = (unsigned short*)(ws + 13762560);   //    262,144
    unsigned short* Abf      = (unsigned short*)(ws + 14024704);   //  3,407,872 (rows >=200 unused)
    float*          partialM = (float*)(ws + 17432576);            // 13,631,488
    unsigned short* hiddenb  = (unsigned short*)(ws + 31064064);   //    524,288
    float*          partial2 = (float*)(ws + 31588352);            //    524,288

    // 1. weight prep (W1 transpose, layer-1 pack, W2 transpose)
    k_prep<<<dim3(210, 32), 256, 0, stream>>>(W1, WU1, WV1, WB1, WC1, W2, W1t, Wt512, W2t);
    // 2. fully fused GNN (both layers) -> Abf
    k_gnn<<<B, 512, 0, stream>>>(x_mod, ei, si, embed, WU0, WV0, WB0, WC0, WA0, WA1,
                                 Wt512, Abf);
    // 3. MLP hidden: (256x6656) @ (6656x1024), split-K=13 -> partialM
    k_gemm<2><<<dim3(16, 4, NCH), 256, 0, stream>>>(Abf, W1t, partialM, MLP_IN, 16, MLP_HID);
    // 4. reduce + bias + relu -> hiddenb bf16
    k_mred<<<256 * MLP_HID / 256, 256, 0, stream>>>(partialM, b1, hiddenb);
    // 5. head GEMM: (256x1024) @ (1024x128), split-K=4 -> partial2
    k_gemm<2><<<dim3(2, 4, 4), 256, 0, stream>>>(hiddenb, W2t, partial2, MLP_HID, 8, 128);
    // 6. finalize: reduce + graph postprocess
    k_fin<<<B, 128, 0, stream>>>(partial2, b2, A, x_mod, out);
}

// Round 7
// 56.479 us; speedup vs baseline: 1.6998x; 1.1724x over previous
//
#include <hip/hip_runtime.h>
#include <math.h>

// Problem constants
#define B       200
#define V       40
#define FIN     16
#define H       128
#define NSW     12
#define NE      40
#define M       52      // NE + NSW
#define MLP_HID 1024
#define OUTD    104     // M + V + NSW
#define MLP_IN  6656    // (NSW + V) * H
#define ZDIM    144
#define ZCDIM   132
#define NCH     13      // MLP split-K chunks
#define X1LD    136     // x1 LDS row stride (shorts)
#define MAXD    16      // max adjacency degree

typedef __attribute__((ext_vector_type(8))) short bf16x8;
typedef __attribute__((ext_vector_type(4))) float f32x4;

__device__ __forceinline__ float sigmoidf(float x) {
    return 1.0f / (1.0f + expf(-x));
}
__device__ __forceinline__ unsigned short f2b(float x) {  // fp32 -> bf16 RNE
    unsigned int u = __float_as_uint(x);
    u += 0x7fffu + ((u >> 16) & 1u);
    return (unsigned short)(u >> 16);
}
__device__ __forceinline__ float b2f(unsigned short s) {
    return __uint_as_float(((unsigned int)s) << 16);
}

// ---------------- weight prep (small mats only; W1 handled inside k_mlp) ----------------
// bx<64: W2 (1024x104) -> W2t[col][k] (cols>=104 zero), 128x1024
// 64<=bx<104: {WU1,WV1,WB1,WC1,WA1} -> Wt640[col][f], 640x128
// 104<=bx<112: {WU0,WV0,WB0,WC0} -> W0t[col][k] 512x32, k>=16 zero
__global__ __launch_bounds__(256) void k_prep(
        const float* __restrict__ WU0, const float* __restrict__ WV0,
        const float* __restrict__ WB0, const float* __restrict__ WC0,
        const float* __restrict__ WU1, const float* __restrict__ WV1,
        const float* __restrict__ WB1, const float* __restrict__ WC1,
        const float* __restrict__ WA1, const float* __restrict__ W2,
        unsigned short* __restrict__ W0t, unsigned short* __restrict__ Wt640,
        unsigned short* __restrict__ W2t) {
    int bx = blockIdx.x, tid = threadIdx.x;
    if (bx < 64) {
        int o0 = bx * 2048 + tid * 8;
#pragma unroll
        for (int i = 0; i < 8; ++i) {
            int o = o0 + i; int col = o >> 10, k = o & 1023;
            W2t[o] = (col < OUTD) ? f2b(W2[(size_t)k * OUTD + col]) : (unsigned short)0;
        }
    } else if (bx < 104) {
        int o0 = (bx - 64) * 2048 + tid * 8;
#pragma unroll
        for (int i = 0; i < 8; ++i) {
            int o = o0 + i; int col = o >> 7, f = o & 127;
            int m = col >> 7, hh = col & 127;
            const float* Ws = (m == 0) ? WU1 : (m == 1) ? WV1 : (m == 2) ? WB1
                            : (m == 3) ? WC1 : WA1;
            Wt640[o] = f2b(Ws[f * H + hh]);
        }
    } else {
        int o0 = (bx - 104) * 2048 + tid * 8;
#pragma unroll
        for (int i = 0; i < 8; ++i) {
            int o = o0 + i; int col = o >> 5, k = o & 31;
            int m = col >> 7, hh = col & 127;
            const float* Ws = (m == 0) ? WU0 : (m == 1) ? WV0 : (m == 2) ? WB0 : WC0;
            W0t[o] = (k < FIN) ? f2b(Ws[k * H + hh]) : (unsigned short)0;
        }
    }
}

// ---------------- fully fused GNN (MFMA proj, adjacency-list message passing) ----------------
// one block per batch, 512 threads (8 waves), ~78 KB LDS
__global__ __launch_bounds__(512) void k_gnn(const float* __restrict__ x,
        const int* __restrict__ ei, const int* __restrict__ si,
        const float* __restrict__ embed, const float* __restrict__ WA0,
        const unsigned short* __restrict__ W0t,
        const unsigned short* __restrict__ Wt640,
        unsigned short* __restrict__ Abf) {
    int b = blockIdx.x, tid = threadIdx.x;
    __shared__ unsigned short xb[48 * 40];      // x bf16, rows 40-47 & k 16-31 zero
    __shared__ unsigned short uvbc[V * 512];    // [row][m*128+h] (L0, then L1)
    __shared__ unsigned short x1l[64 * X1LD];   // rows 0-39 x1; 48-59 relu(e0); rest 0
    __shared__ float gL[NSW * H];               // gates (L0, then L1)
    __shared__ float sA1l[NSW * H];
    __shared__ int   nbr[V][MAXD];
    __shared__ int   deg[V];

    int h = tid & 127, sub = tid >> 7;
    int lane = tid & 63, wv = tid >> 6;
    int lr = lane & 15, lk = lane >> 4;
    int n0w = wv * 64;

    // ---- phase 1: load x (bf16, padded), zero deg + x1l pad rows ----
    for (int o = tid; o < 48 * 32; o += 512) {
        int r = o >> 5, k = o & 31;
        float v = (r < V && k < FIN) ? x[(size_t)b * V * FIN + r * FIN + k] : 0.f;
        xb[r * 40 + k] = f2b(v);
    }
    if (tid < V) deg[tid] = 0;
    for (int o = tid; o < 12 * 128; o += 512) {
        int rr = o >> 7;
        int row = (rr < 8) ? 40 + rr : 60 + (rr - 8);
        x1l[row * X1LD + (o & 127)] = 0;
    }
    __syncthreads();

    // ---- phase 2: adjacency build + proj0 MFMA -> uvbc(L0) ----
    if (tid < NE) {
        int i = ei[tid], j = ei[NE + tid];
        int p = atomicAdd(&deg[i], 1); if (p < MAXD) nbr[i][p] = j;
        int q = atomicAdd(&deg[j], 1); if (q < MAXD) nbr[j][q] = i;
    } else if (tid < NE + NSW) {
        int k = tid - NE;
        int i = si[k], j = si[NSW + k];
        int p = atomicAdd(&deg[i], 1); if (p < MAXD) nbr[i][p] = j | ((k + 1) << 8);
    }
    {
        f32x4 acc[3][4];
#pragma unroll
        for (int rf = 0; rf < 3; ++rf)
#pragma unroll
            for (int cf = 0; cf < 4; ++cf) acc[rf][cf] = (f32x4){0.f, 0.f, 0.f, 0.f};
        int kseg = lk * 8;
        bf16x8 a0 = *(const bf16x8*)&xb[lr * 40 + kseg];
        bf16x8 a1 = *(const bf16x8*)&xb[(16 + lr) * 40 + kseg];
        bf16x8 a2 = *(const bf16x8*)&xb[(32 + lr) * 40 + kseg];
#pragma unroll
        for (int cf = 0; cf < 4; ++cf) {
            bf16x8 bf = *(const bf16x8*)&W0t[(n0w + cf * 16 + lr) * 32 + kseg];
            acc[0][cf] = __builtin_amdgcn_mfma_f32_16x16x32_bf16(a0, bf, acc[0][cf], 0, 0, 0);
            acc[1][cf] = __builtin_amdgcn_mfma_f32_16x16x32_bf16(a1, bf, acc[1][cf], 0, 0, 0);
            acc[2][cf] = __builtin_amdgcn_mfma_f32_16x16x32_bf16(a2, bf, acc[2][cf], 0, 0, 0);
        }
#pragma unroll
        for (int rf = 0; rf < 3; ++rf)
#pragma unroll
            for (int cf = 0; cf < 4; ++cf)
#pragma unroll
                for (int r = 0; r < 4; ++r) {
                    int row = rf * 16 + lk * 4 + r;
                    if (row < V) uvbc[row * 512 + n0w + cf * 16 + lr] = f2b(acc[rf][cf][r]);
                }
    }
    __syncthreads();

    // ---- phase 3: layer-0 gates -> gL; relu(e0) -> x1l rows 48..59 ----
    {
        float sA0 = 0.f;
#pragma unroll
        for (int f = 0; f < FIN; ++f) sA0 += embed[FIN + f] * WA0[f * H + h];
        for (int k = sub; k < NSW; k += 4) {
            int i = si[k], j = si[NSW + k];
            float e0 = sA0 + b2f(uvbc[i * 512 + 256 + h]) + b2f(uvbc[j * 512 + 384 + h]);
            gL[k * H + h] = sigmoidf(e0);
            x1l[(48 + k) * X1LD + h] = f2b(fmaxf(e0, 0.f));
        }
    }
    __syncthreads();

    // ---- phase 4: x1 via adjacency -> x1l rows 0..39 ----
    for (int i = sub * 10; i < sub * 10 + 10; ++i) {
        float acc = b2f(uvbc[i * 512 + h]);          // Ux
        int d = deg[i]; if (d > MAXD) d = MAXD;
        for (int p = 0; p < d; ++p) {
            int ent = nbr[i][p];
            float vv = b2f(uvbc[(ent & 255) * 512 + 128 + h]);   // Vx[j]
            int g = ent >> 8;
            if (g) vv *= gL[(g - 1) * H + h];
            acc += vv;
        }
        x1l[i * X1LD + h] = f2b(fmaxf(acc, 0.f));    // layer 0: no residual
    }
    __syncthreads();

    // ---- phase 5: proj1 + sA1 MFMA -> uvbc(L1), sA1l ----
    {
        f32x4 acc[3][4], accs = (f32x4){0.f, 0.f, 0.f, 0.f};
#pragma unroll
        for (int rf = 0; rf < 3; ++rf)
#pragma unroll
            for (int cf = 0; cf < 4; ++cf) acc[rf][cf] = (f32x4){0.f, 0.f, 0.f, 0.f};
#pragma unroll
        for (int kk = 0; kk < 4; ++kk) {
            int kseg = kk * 32 + lk * 8;
            bf16x8 a0 = *(const bf16x8*)&x1l[lr * X1LD + kseg];
            bf16x8 a1 = *(const bf16x8*)&x1l[(16 + lr) * X1LD + kseg];
            bf16x8 a2 = *(const bf16x8*)&x1l[(32 + lr) * X1LD + kseg];
            bf16x8 as = *(const bf16x8*)&x1l[(48 + lr) * X1LD + kseg];
#pragma unroll
            for (int cf = 0; cf < 4; ++cf) {
                bf16x8 bf = *(const bf16x8*)&Wt640[(size_t)(n0w + cf * 16 + lr) * H + kseg];
                acc[0][cf] = __builtin_amdgcn_mfma_f32_16x16x32_bf16(a0, bf, acc[0][cf], 0, 0, 0);
                acc[1][cf] = __builtin_amdgcn_mfma_f32_16x16x32_bf16(a1, bf, acc[1][cf], 0, 0, 0);
                acc[2][cf] = __builtin_amdgcn_mfma_f32_16x16x32_bf16(a2, bf, acc[2][cf], 0, 0, 0);
            }
            bf16x8 bs = *(const bf16x8*)&Wt640[(size_t)(512 + wv * 16 + lr) * H + kseg];
            accs = __builtin_amdgcn_mfma_f32_16x16x32_bf16(as, bs, accs, 0, 0, 0);
        }
#pragma unroll
        for (int rf = 0; rf < 3; ++rf)
#pragma unroll
            for (int cf = 0; cf < 4; ++cf)
#pragma unroll
                for (int r = 0; r < 4; ++r) {
                    int row = rf * 16 + lk * 4 + r;
                    if (row < V) uvbc[row * 512 + n0w + cf * 16 + lr] = f2b(acc[rf][cf][r]);
                }
#pragma unroll
        for (int r = 0; r < 4; ++r) {
            int sr = lk * 4 + r;
            if (sr < NSW) sA1l[sr * H + wv * 16 + lr] = accs[r];
        }
    }
    __syncthreads();

    // ---- phase 6: layer-1 gates -> gL; s2 switch rows -> Abf ----
    for (int k = sub; k < NSW; k += 4) {
        int i = si[k], j = si[NSW + k];
        float e1 = sA1l[k * H + h] + b2f(uvbc[i * 512 + 256 + h]) + b2f(uvbc[j * 512 + 384 + h]);
        gL[k * H + h] = sigmoidf(e1);
        float s1 = b2f(x1l[(48 + k) * X1LD + h]);
        Abf[(size_t)b * MLP_IN + k * H + h] = f2b(s1 + fmaxf(e1, 0.f));
    }
    __syncthreads();

    // ---- phase 7: x2 via adjacency (residual) -> Abf ----
    for (int i = sub * 10; i < sub * 10 + 10; ++i) {
        float acc = b2f(uvbc[i * 512 + h]);
        int d = deg[i]; if (d > MAXD) d = MAXD;
        for (int p = 0; p < d; ++p) {
            int ent = nbr[i][p];
            float vv = b2f(uvbc[(ent & 255) * 512 + 128 + h]);
            int g = ent >> 8;
            if (g) vv *= gL[(g - 1) * H + h];
            acc += vv;
        }
        float x2 = b2f(x1l[i * X1LD + h]) + fmaxf(acc, 0.f);
        Abf[(size_t)b * MLP_IN + NSW * H + i * H + h] = f2b(x2);
    }
}

// ---------------- MLP GEMM with fused W1 transpose+bf16 convert ----------------
// partial[z][m][n] = Abf[m][k-chunk] @ W1[k-chunk][n]; grid(16,4,NCH), nk=16
__global__ __launch_bounds__(256) void k_mlp(const unsigned short* __restrict__ A,
        const float* __restrict__ W1, float* __restrict__ partial) {
    const int NK = 16;
    int tid = threadIdx.x;
    int lane = tid & 63, wvv = tid >> 6;
    int wr = (wvv >> 1) * 32, wc = (wvv & 1) * 32;
    int n0 = blockIdx.x * 64, m0 = blockIdx.y * 64;
    int kbase = blockIdx.z * NK * 32;

    __shared__ __align__(16) unsigned short a_lds[64 * 40];
    __shared__ __align__(16) unsigned short b_lds[64 * 40];

    f32x4 acc00 = {0,0,0,0}, acc01 = {0,0,0,0}, acc10 = {0,0,0,0}, acc11 = {0,0,0,0};

    int srow = tid >> 2, sseg = tid & 3;
    const int4* gA = (const int4*)(A + (size_t)(m0 + srow) * MLP_IN + kbase + sseg * 8);
    int lwsA = srow * 40 + sseg * 8;

    int bcol = tid & 63, bkg = tid >> 6;
    const float* gW = W1 + (size_t)(kbase + bkg * 8) * MLP_HID + n0 + bcol;
    int lwsB = bcol * 40 + bkg * 8;

    int a_off = (wr + (lane & 15)) * 40 + (lane >> 4) * 8;
    int b_off = (wc + (lane & 15)) * 40 + (lane >> 4) * 8;

    int4 ra = gA[0];
    float rfv[8];
#pragma unroll
    for (int i = 0; i < 8; ++i) rfv[i] = gW[(size_t)i * MLP_HID];

    for (int kk = 0; kk < NK; ++kk) {
        *(int4*)&a_lds[lwsA] = ra;
        union { unsigned short us[8]; int4 v; } pk;
#pragma unroll
        for (int i = 0; i < 8; ++i) pk.us[i] = f2b(rfv[i]);
        *(int4*)&b_lds[lwsB] = pk.v;
        __syncthreads();
        if (kk + 1 < NK) {
            ra = gA[(kk + 1) * 4];
            const float* g2 = gW + (size_t)(kk + 1) * 32 * MLP_HID;
#pragma unroll
            for (int i = 0; i < 8; ++i) rfv[i] = g2[(size_t)i * MLP_HID];
        }
        bf16x8 a0 = *(const bf16x8*)&a_lds[a_off];
        bf16x8 a1 = *(const bf16x8*)&a_lds[a_off + 16 * 40];
        bf16x8 b0 = *(const bf16x8*)&b_lds[b_off];
        bf16x8 b1 = *(const bf16x8*)&b_lds[b_off + 16 * 40];
        acc00 = __builtin_amdgcn_mfma_f32_16x16x32_bf16(a0, b0, acc00, 0, 0, 0);
        acc01 = __builtin_amdgcn_mfma_f32_16x16x32_bf16(a0, b1, acc01, 0, 0, 0);
        acc10 = __builtin_amdgcn_mfma_f32_16x16x32_bf16(a1, b0, acc10, 0, 0, 0);
        acc11 = __builtin_amdgcn_mfma_f32_16x16x32_bf16(a1, b1, acc11, 0, 0, 0);
        __syncthreads();
    }

    int crow = (lane >> 4) * 4, ccol = lane & 15;
    int row0 = m0 + wr + crow, row1 = row0 + 16;
    int col0 = n0 + wc + ccol, col1 = col0 + 16;
    float* dst = partial + (size_t)blockIdx.z * 256 * MLP_HID;
#pragma unroll
    for (int r = 0; r < 4; ++r) {
        dst[(size_t)(row0 + r) * MLP_HID + col0] = acc00[r];
        dst[(size_t)(row0 + r) * MLP_HID + col1] = acc01[r];
        dst[(size_t)(row1 + r) * MLP_HID + col0] = acc10[r];
        dst[(size_t)(row1 + r) * MLP_HID + col1] = acc11[r];
    }
}

// ---------------- generic bf16 MFMA GEMM (head): f32 split-K partial out ----------------
template<int MODE>
__global__ __launch_bounds__(256) void k_gemm(const unsigned short* __restrict__ A,
        const unsigned short* __restrict__ Bt, void* __restrict__ Cout,
        int K, int nk, int ldc) {
    int tid = threadIdx.x;
    int lane = tid & 63, wv = tid >> 6;
    int wr = (wv >> 1) * 32, wc = (wv & 1) * 32;
    int n0 = blockIdx.x * 64, m0 = blockIdx.y * 64;
    size_t kbase = (size_t)blockIdx.z * nk * 32;

    __shared__ __align__(16) unsigned short a_lds[64 * 40];
    __shared__ __align__(16) unsigned short b_lds[64 * 40];

    f32x4 acc00 = {0,0,0,0}, acc01 = {0,0,0,0}, acc10 = {0,0,0,0}, acc11 = {0,0,0,0};

    int srow = tid >> 2, sseg = tid & 3;
    const int4* gA = (const int4*)(A + (size_t)(m0 + srow) * K + kbase + sseg * 8);
    const int4* gB = (const int4*)(Bt + (size_t)(n0 + srow) * K + kbase + sseg * 8);
    int lws = srow * 40 + sseg * 8;

    int a_off = (wr + (lane & 15)) * 40 + (lane >> 4) * 8;
    int b_off = (wc + (lane & 15)) * 40 + (lane >> 4) * 8;

    int4 ra = gA[0], rb = gB[0];
    for (int kk = 0; kk < nk; ++kk) {
        *(int4*)&a_lds[lws] = ra;
        *(int4*)&b_lds[lws] = rb;
        __syncthreads();
        if (kk + 1 < nk) { ra = gA[(kk + 1) * 4]; rb = gB[(kk + 1) * 4]; }
        bf16x8 a0 = *(const bf16x8*)&a_lds[a_off];
        bf16x8 a1 = *(const bf16x8*)&a_lds[a_off + 16 * 40];
        bf16x8 b0 = *(const bf16x8*)&b_lds[b_off];
        bf16x8 b1 = *(const bf16x8*)&b_lds[b_off + 16 * 40];
        acc00 = __builtin_amdgcn_mfma_f32_16x16x32_bf16(a0, b0, acc00, 0, 0, 0);
        acc01 = __builtin_amdgcn_mfma_f32_16x16x32_bf16(a0, b1, acc01, 0, 0, 0);
        acc10 = __builtin_amdgcn_mfma_f32_16x16x32_bf16(a1, b0, acc10, 0, 0, 0);
        acc11 = __builtin_amdgcn_mfma_f32_16x16x32_bf16(a1, b1, acc11, 0, 0, 0);
        __syncthreads();
    }

    int crow = (lane >> 4) * 4, ccol = lane & 15;
    int row0 = m0 + wr + crow, row1 = row0 + 16;
    int col0 = n0 + wc + ccol, col1 = col0 + 16;
    float* dst = (float*)Cout + (size_t)blockIdx.z * (gridDim.y * 64) * ldc;
#pragma unroll
    for (int r = 0; r < 4; ++r) {
        dst[(size_t)(row0 + r) * ldc + col0] = acc00[r];
        dst[(size_t)(row0 + r) * ldc + col1] = acc01[r];
        dst[(size_t)(row1 + r) * ldc + col0] = acc10[r];
        dst[(size_t)(row1 + r) * ldc + col1] = acc11[r];
    }
}

// reduce MLP split-K partials + bias + relu -> bf16 hidden
__global__ void k_mred(const float* __restrict__ partial, const float* __restrict__ b1,
                       unsigned short* __restrict__ hiddenb) {
    int i = blockIdx.x * 256 + threadIdx.x;   // < 256*1024
    float s = b1[i & (MLP_HID - 1)];
#pragma unroll
    for (int z = 0; z < NCH; ++z) s += partial[(size_t)z * 256 * MLP_HID + i];
    hiddenb[i] = f2b(fmaxf(s, 0.f));
}

// ---------------- finalize: reduce head partials + postprocess ----------------
__global__ __launch_bounds__(128) void k_fin(const float* __restrict__ partial2,
        const float* __restrict__ b2, const float* __restrict__ A,
        const float* __restrict__ x_mod, float* __restrict__ outp) {
    int b = blockIdx.x;
    int tid = threadIdx.x;
    __shared__ float o[OUTD];
    __shared__ float gt[M], vv[V], pfc[M], qfc[M];

    if (tid < OUTD) {
        float s = b2[tid];
#pragma unroll
        for (int z = 0; z < 4; ++z) s += partial2[(size_t)z * 256 * 128 + b * 128 + tid];
        o[tid] = s;
    }
    __syncthreads();

    if (tid < M) {
        float g = (tid < M - NSW) ? 1.0f : sigmoidf(o[M + V + (tid - (M - NSW))]);
        gt[tid] = g;
        pfc[tid] = g * o[tid];
    }
    if (tid < V) vv[tid] = (tid == 0) ? 1.0f : o[M + tid];
    __syncthreads();

    if (tid < M) {
        float acc = 0.f;
        for (int x = 0; x < V; ++x) acc += vv[x] * A[x * M + tid];
        qfc[tid] = gt[tid] * acc;
    }
    __syncthreads();

    float* zb = outp + (size_t)b * ZDIM;
    if (tid < M) zb[tid] = pfc[tid];
    if (tid < V) zb[M + tid] = vv[tid];
    if (tid < M) zb[M + V + tid] = gt[tid];

    float* zcb = outp + (size_t)B * ZDIM + (size_t)b * ZCDIM;
    if (tid < M) zcb[tid] = qfc[tid];
    if (tid < V) {
        float accp = 0.f, accq = 0.f;
        for (int m = 0; m < M; ++m) {
            float a = A[tid * M + m];
            accp += a * pfc[m];
            accq += a * qfc[m];
        }
        zcb[M + tid]     = x_mod[(size_t)(b * V + tid) * FIN + 0] + accp;
        zcb[M + V + tid] = x_mod[(size_t)(b * V + tid) * FIN + 1] + accq;
    }
}

extern "C" void kernel_launch(void* const* d_in, const int* in_sizes, int n_in,
                              void* d_out, int out_size, void* d_ws, size_t ws_size,
                              hipStream_t stream) {
    const float* x_mod = (const float*)d_in[0];
    const int*   ei    = (const int*)d_in[1];
    const int*   si    = (const int*)d_in[2];
    const float* A     = (const float*)d_in[3];
    const float* embed = (const float*)d_in[4];
    const float* WU0   = (const float*)d_in[5];
    const float* WV0   = (const float*)d_in[6];
    const float* WA0   = (const float*)d_in[7];
    const float* WB0   = (const float*)d_in[8];
    const float* WC0   = (const float*)d_in[9];
    const float* WU1   = (const float*)d_in[10];
    const float* WV1   = (const float*)d_in[11];
    const float* WA1   = (const float*)d_in[12];
    const float* WB1   = (const float*)d_in[13];
    const float* WC1   = (const float*)d_in[14];
    const float* W1    = (const float*)d_in[15];
    const float* b1    = (const float*)d_in[16];
    const float* W2    = (const float*)d_in[17];
    const float* b2    = (const float*)d_in[18];
    float* out = (float*)d_out;

    // Workspace layout (byte offsets), ~18.5 MB
    char* ws = (char*)d_ws;
    unsigned short* W0t      = (unsigned short*)(ws + 0);          //    32,768
    unsigned short* Wt640    = (unsigned short*)(ws + 32768);      //   163,840
    unsigned short* W2t      = (unsigned short*)(ws + 196608);     //   262,144
    unsigned short* Abf      = (unsigned short*)(ws + 458752);     // 3,407,872 (rows >=200 unused)
    float*          partialM = (float*)(ws + 3866624);             // 13,631,488
    unsigned short* hiddenb  = (unsigned short*)(ws + 17498112);   //   524,288
    float*          partial2 = (float*)(ws + 18022400);            //   524,288

    // 1. small weight prep (W0t, Wt640, W2t) — W1 transpose folded into k_mlp
    k_prep<<<112, 256, 0, stream>>>(WU0, WV0, WB0, WC0, WU1, WV1, WB1, WC1, WA1, W2,
                                    W0t, Wt640, W2t);
    // 2. fully fused GNN (both layers, MFMA projections) -> Abf
    k_gnn<<<B, 512, 0, stream>>>(x_mod, ei, si, embed, WA0, W0t, Wt640, Abf);
    // 3. MLP hidden: (256x6656) @ W1 (f32, transposed on the fly), split-K=13
    k_mlp<<<dim3(16, 4, NCH), 256, 0, stream>>>(Abf, W1, partialM);
    // 4. reduce + bias + relu -> hiddenb bf16
    k_mred<<<256 * MLP_HID / 256, 256, 0, stream>>>(partialM, b1, hiddenb);
    // 5. head GEMM: (256x1024) @ (1024x128), split-K=4 -> partial2
    k_gemm<2><<<dim3(2, 4, 4), 256, 0, stream>>>(hiddenb, W2t, partial2, MLP_HID, 8, 128);
    // 6. finalize: reduce + graph postprocess
    k_fin<<<B, 128, 0, stream>>>(partial2, b2, A, x_mod, out);
}